// Round 13
// baseline (393.600 us; speedup 1.0000x reference)
//
#include <hip/hip_runtime.h>

#define N_NODES 100000
#define NPAD    100352            // padded node count (multiple of 512)
#define N_EDGES 1600000
#define HID 32
#define BN_EPS 1e-5f
#define NXCD 8

// physical XCD id (0..7): s_getreg_b32 hwreg(HW_REG_XCC_ID=20, off=0, size=32)
__device__ __forceinline__ int xcd_id() {
    return (int)(__builtin_amdgcn_s_getreg((31u << 11) | 20u) & 7u);
}

// ============================ main path ============================

// grid-stride: in-degree histogram into THIS XCD's private copy
__global__ void deg_kernel(const int* __restrict__ dst, int* __restrict__ deg_priv) {
    int* dp = deg_priv + xcd_id() * NPAD;
    int stride = gridDim.x * blockDim.x;
    for (int e = blockIdx.x * blockDim.x + threadIdx.x; e < N_EDGES; e += stride)
        atomicAdd(&dp[dst[e]], 1);
}

// per node: deg = sum of 8 private copies; xd[n] = (x*rd, rd)
__global__ void xd_kernel(const int* __restrict__ deg_priv, const float* __restrict__ x,
                          float4* __restrict__ xd) {
    int n = blockIdx.x * blockDim.x + threadIdx.x;
    if (n >= N_NODES) return;
    int deg = 0;
#pragma unroll
    for (int k = 0; k < NXCD; ++k) deg += deg_priv[k * NPAD + n];
    float rd = rsqrtf(1.0f + (float)deg);
    xd[n] = make_float4(x[3 * n] * rd, x[3 * n + 1] * rd, x[3 * n + 2] * rd, rd);
}

// grid-stride: S_priv[xcd][dst] += xd[src]  (3 float atomics into a 16B-aligned
// slot -> always within one 64B line; line touched by ONE XCD only)
__global__ void scatter_kernel(const int* __restrict__ src, const int* __restrict__ dst,
                               const float4* __restrict__ xd, float* __restrict__ S_priv) {
    float* sp = S_priv + (size_t)xcd_id() * (NPAD * 4);
    int stride = gridDim.x * blockDim.x;
    for (int e = blockIdx.x * blockDim.x + threadIdx.x; e < N_EDGES; e += stride) {
        int s = src[e], d = dst[e];
        float4 v = xd[s];
        float* p = sp + (size_t)d * 4;
        atomicAdd(p + 0, v.x);
        atomicAdd(p + 1, v.y);
        atomicAdd(p + 2, v.z);
    }
}

// per node: S = self + sum of 8 private copies; write S4; fused 9-scalar BN stats
__global__ void sreduce_kernel(const float* __restrict__ S_priv, const float4* __restrict__ xd,
                               float4* __restrict__ S4, float* __restrict__ stats) {
    __shared__ float ls[4][9];
    int tid = threadIdx.x;
    int n = blockIdx.x * blockDim.x + tid;
    float st[9];
#pragma unroll
    for (int q = 0; q < 9; ++q) st[q] = 0.f;
    if (n < N_NODES) {
        float4 self = xd[n];
        float sx = self.x, sy = self.y, sz = self.z;
#pragma unroll
        for (int k = 0; k < NXCD; ++k) {
            const float* p = S_priv + (size_t)k * (NPAD * 4) + (size_t)n * 4;
            sx += p[0]; sy += p[1]; sz += p[2];
        }
        S4[n] = make_float4(sx, sy, sz, self.w);
        float ax = self.w * sx, ay = self.w * sy, az = self.w * sz;
        st[0] = ax; st[1] = ay; st[2] = az;
        st[3] = ax * ax; st[4] = ax * ay; st[5] = ax * az;
        st[6] = ay * ay; st[7] = ay * az; st[8] = az * az;
    }
    for (int m = 1; m < 64; m <<= 1)
#pragma unroll
        for (int q = 0; q < 9; ++q) st[q] += __shfl_xor(st[q], m);
    int wv = tid >> 6;
    if ((tid & 63) == 0)
#pragma unroll
        for (int q = 0; q < 9; ++q) ls[wv][q] = st[q];
    __syncthreads();
    if (tid < 9) {
        float s = ls[0][tid] + ls[1][tid] + ls[2][tid] + ls[3][tid];
        atomicAdd(&stats[tid], s);
    }
}

// fused BN-fold + PReLU streaming output
__global__ void final_out_kernel(const float4* __restrict__ S4, const float* __restrict__ stats,
                                 const float* __restrict__ W, const float* __restrict__ bb,
                                 const float* __restrict__ gamma, const float* __restrict__ beta,
                                 const float* __restrict__ prelu, float* __restrict__ out) {
    __shared__ float cb[4 * HID];
    int tid = threadIdx.x;
    if (tid < HID) {
        int c = tid;
        float m1x = stats[0], m1y = stats[1], m1z = stats[2];
        float Mxx = stats[3], Mxy = stats[4], Mxz = stats[5];
        float Myy = stats[6], Myz = stats[7], Mzz = stats[8];
        float w0 = W[c], w1 = W[HID + c], w2 = W[2 * HID + c];
        const float invn = 1.0f / (float)N_NODES;
        float m1w = m1x * w0 + m1y * w1 + m1z * w2;
        float mean = m1w * invn + bb[c];
        float quad = w0 * w0 * Mxx + w1 * w1 * Myy + w2 * w2 * Mzz
                   + 2.f * (w0 * w1 * Mxy + w0 * w2 * Mxz + w1 * w2 * Myz);
        float ex2 = quad * invn + 2.f * bb[c] * m1w * invn + bb[c] * bb[c];
        float var = ex2 - mean * mean;
        float sc = gamma[c] * rsqrtf(var + BN_EPS);
        cb[c] = w0 * sc;
        cb[HID + c] = w1 * sc;
        cb[2 * HID + c] = w2 * sc;
        cb[3 * HID + c] = bb[c] * sc + (beta[c] - mean * sc);
    }
    __syncthreads();
    float a = prelu[0];
    int stride = gridDim.x * blockDim.x;
    for (int t = blockIdx.x * blockDim.x + tid; t < N_NODES * HID; t += stride) {
        int n = t >> 5, c = t & 31;
        float4 s = S4[n];
        float y = s.w * (s.x * cb[c] + s.y * cb[HID + c] + s.z * cb[2 * HID + c])
                + cb[3 * HID + c];
        out[t] = y >= 0.f ? y : a * y;
    }
}

// ============================ fallback (round-4) path ============================

__global__ void fb_count_kernel(const int* __restrict__ dst, int* __restrict__ cnt) {
    int e = blockIdx.x * blockDim.x + threadIdx.x;
    if (e < N_EDGES) atomicAdd(&cnt[dst[e]], 1);
}

__global__ void fb_xd_kernel(const float* __restrict__ x, const int* __restrict__ cnt,
                             float4* __restrict__ xd, float4* __restrict__ S4) {
    int n = blockIdx.x * blockDim.x + threadIdx.x;
    if (n >= N_NODES) return;
    float rd = rsqrtf(1.0f + (float)cnt[n]);
    float4 v = make_float4(x[3 * n] * rd, x[3 * n + 1] * rd, x[3 * n + 2] * rd, rd);
    xd[n] = v;
    S4[n] = v;
}

__global__ void fb_scatter_kernel(const int* __restrict__ src, const int* __restrict__ dst,
                                  const float4* __restrict__ xd, float4* __restrict__ S4) {
    int e = blockIdx.x * blockDim.x + threadIdx.x;
    if (e >= N_EDGES) return;
    int s = src[e], d = dst[e];
    float4 v = xd[s];
    float* p = (float*)&S4[d];
    atomicAdd(p + 0, v.x);
    atomicAdd(p + 1, v.y);
    atomicAdd(p + 2, v.z);
}

__global__ void fb_stats_kernel(const float4* __restrict__ S4, float* __restrict__ stats) {
    __shared__ float ls[4][9];
    int tid = threadIdx.x;
    int n = blockIdx.x * blockDim.x + tid;
    float st[9];
#pragma unroll
    for (int q = 0; q < 9; ++q) st[q] = 0.f;
    if (n < N_NODES) {
        float4 s = S4[n];
        float ax = s.w * s.x, ay = s.w * s.y, az = s.w * s.z;
        st[0] = ax; st[1] = ay; st[2] = az;
        st[3] = ax * ax; st[4] = ax * ay; st[5] = ax * az;
        st[6] = ay * ay; st[7] = ay * az; st[8] = az * az;
    }
    for (int m = 1; m < 64; m <<= 1)
#pragma unroll
        for (int q = 0; q < 9; ++q) st[q] += __shfl_xor(st[q], m);
    int wv = tid >> 6;
    if ((tid & 63) == 0)
#pragma unroll
        for (int q = 0; q < 9; ++q) ls[wv][q] = st[q];
    __syncthreads();
    if (tid < 9) {
        float s = ls[0][tid] + ls[1][tid] + ls[2][tid] + ls[3][tid];
        atomicAdd(&stats[tid], s);
    }
}

// ============================ launch ============================

extern "C" void kernel_launch(void* const* d_in, const int* in_sizes, int n_in,
                              void* d_out, int out_size, void* d_ws, size_t ws_size,
                              hipStream_t stream) {
    const float* x     = (const float*)d_in[0];
    const int*   ei    = (const int*)d_in[1];   // [2, E]: src row then dst row
    const float* W     = (const float*)d_in[2];
    const float* b     = (const float*)d_in[3];
    const float* gamma = (const float*)d_in[4];
    const float* beta  = (const float*)d_in[5];
    const float* prelu = (const float*)d_in[6];

    const int* src = ei;
    const int* dst = ei + N_EDGES;
    char* ws = (char*)d_ws;
    float* out = (float*)d_out;

    // ---- ws layout (main path), total 19,256,384 B ----
    // [zeroed in one memset: 0 .. 16,056,384)
    // deg_priv @ 0           int[8][NPAD]      (3,211,264)
    // S_priv   @ 3,211,264   float[8][NPAD*4]  (12,845,056) -> 16,056,320
    // stats    @ 16,056,320  float[16]         (64)         -> 16,056,384
    // xd       @ 16,056,384  float4[100000]    (1,600,000)  -> 17,656,384 (16B-aligned)
    // S4       @ 17,656,384  float4[100000]    (1,600,000)  -> 19,256,384
    const size_t NEEDED = 19256384;

    if (ws_size >= NEEDED) {
        int*    deg_priv = (int*)(ws);
        float*  S_priv   = (float*)(ws + 3211264);
        float*  stats    = (float*)(ws + 16056320);
        float4* xd       = (float4*)(ws + 16056384);
        float4* S4       = (float4*)(ws + 17656384);

        hipMemsetAsync(ws, 0, 16056384, stream);
        deg_kernel<<<2048, 256, 0, stream>>>(dst, deg_priv);
        xd_kernel<<<(N_NODES + 255) / 256, 256, 0, stream>>>(deg_priv, x, xd);
        scatter_kernel<<<2048, 256, 0, stream>>>(src, dst, xd, S_priv);
        sreduce_kernel<<<(N_NODES + 255) / 256, 256, 0, stream>>>(S_priv, xd, S4, stats);
        final_out_kernel<<<2048, 256, 0, stream>>>(S4, stats, W, b, gamma, beta, prelu, out);
    } else {
        // fallback: round-4 direct-atomic path (ws need ~3.6 MB)
        int*    cnt   = (int*)(ws);
        float*  stats = (float*)(ws + 400000);
        float4* xd    = (float4*)(ws + 400640);
        float4* S4    = (float4*)(ws + 2000640);

        hipMemsetAsync(ws, 0, 400064, stream);
        fb_count_kernel<<<(N_EDGES + 255) / 256, 256, 0, stream>>>(dst, cnt);
        fb_xd_kernel<<<(N_NODES + 255) / 256, 256, 0, stream>>>(x, cnt, xd, S4);
        fb_scatter_kernel<<<(N_EDGES + 255) / 256, 256, 0, stream>>>(src, dst, xd, S4);
        fb_stats_kernel<<<(N_NODES + 255) / 256, 256, 0, stream>>>(S4, stats);
        final_out_kernel<<<2048, 256, 0, stream>>>(S4, stats, W, b, gamma, beta, prelu, out);
    }
}

// Round 14
// 136.349 us; speedup vs baseline: 2.8867x; 2.8867x over previous
//
#include <hip/hip_runtime.h>

#define N_NODES 100000
#define N_EDGES 1600000
#define HID 32
#define BN_EPS 1e-5f

#define BSZ   128                    // nodes per bucket
#define NBUCK 782                    // 782*128 = 100096 >= 100000
#define CAP   3072                   // edge capacity per bucket (avg 2047, sigma~45)
#define NSL   256                    // edge slices
#define EPSL  6250                   // 256*6250 = 1,600,000 exactly
#define SRC_MASK 0x1FFFFu

// ============================ main path ============================

// One pass over edges: LDS hist(782) -> global bump-allocate bucket bases ->
// local scan -> LDS bucket-sort stage -> burst copy-out. No scattered stores;
// only 782 global atomics per block (write-through cost ~6MB total).
__global__ __launch_bounds__(1024)
void bin_kernel(const int* __restrict__ src, const int* __restrict__ dst,
                int* __restrict__ gcur, unsigned* __restrict__ ebuf) {
    __shared__ unsigned stageP[EPSL];          // 25,000 B
    __shared__ unsigned short stageB[EPSL];    // 12,500 B
    __shared__ int hist[NBUCK], curs[NBUCK], delta[NBUCK];
    __shared__ int sc[1024];
    int tid = threadIdx.x, blk = blockIdx.x;
    int e0 = blk * EPSL;

    unsigned pk[7]; int bk[7];
#pragma unroll
    for (int i = 0; i < 7; ++i) {
        int j = tid + i * 1024;
        if (j < EPSL) {
            int e = e0 + j;
            int d = dst[e];
            bk[i] = d >> 7;
            pk[i] = ((unsigned)(d & (BSZ - 1)) << 17) | (unsigned)src[e];
        } else bk[i] = -1;
    }
    for (int j = tid; j < NBUCK; j += 1024) hist[j] = 0;
    __syncthreads();
#pragma unroll
    for (int i = 0; i < 7; ++i)
        if (bk[i] >= 0) atomicAdd(&hist[bk[i]], 1);
    __syncthreads();
    // global bump-allocate (one atomic per bucket) while scan proceeds
    if (tid < NBUCK) delta[tid] = tid * CAP + atomicAdd(&gcur[tid], hist[tid]);
    // inclusive Hillis-Steele scan over 1024 (NBUCK padded with 0)
    int h = (tid < NBUCK) ? hist[tid] : 0;
    sc[tid] = h;
    __syncthreads();
    for (int off = 1; off < 1024; off <<= 1) {
        int v = (tid >= off) ? sc[tid - off] : 0;
        __syncthreads();
        sc[tid] += v;
        __syncthreads();
    }
    if (tid < NBUCK) {
        int loff = sc[tid] - h;          // block-local exclusive offset
        curs[tid] = loff;
        delta[tid] -= loff;              // global_addr = local_pos + delta[b]
    }
    __syncthreads();
    // stage into LDS, bucket-sorted
#pragma unroll
    for (int i = 0; i < 7; ++i)
        if (bk[i] >= 0) {
            int pos = atomicAdd(&curs[bk[i]], 1);
            stageP[pos] = pk[i];
            stageB[pos] = (unsigned short)bk[i];
        }
    __syncthreads();
    // burst copy-out: consecutive staged entries -> consecutive global slots per run
    for (int j = tid; j < EPSL; j += 1024) {
        int b = stageB[j];
        ebuf[j + delta[b]] = stageP[j];
    }
}

// per bucket: degree hist (per-wave replicated) from its region; write xd
__global__ void degxd_kernel(const unsigned* __restrict__ ebuf, const int* __restrict__ gcur,
                             const float* __restrict__ x, float4* __restrict__ xd) {
    __shared__ int h4[4][BSZ];
    int tid = threadIdx.x, b = blockIdx.x;
    int wv = tid >> 6;
    for (int j = tid; j < 4 * BSZ; j += 256) ((int*)h4)[j] = 0;
    __syncthreads();
    int cnt = gcur[b];
    int base = b * CAP;
    for (int e = tid; e < cnt; e += 256)
        atomicAdd(&h4[wv][ebuf[base + e] >> 17], 1);
    __syncthreads();
    if (tid < BSZ) {
        int n = (b << 7) + tid;
        if (n < N_NODES) {
            int deg = h4[0][tid] + h4[1][tid] + h4[2][tid] + h4[3][tid];
            float rd = rsqrtf(1.0f + (float)deg);
            xd[n] = make_float4(x[3 * n] * rd, x[3 * n + 1] * rd, x[3 * n + 2] * rd, rd);
        }
    }
}

// per bucket: gather xd[src], per-wave-replicated LDS S accumulate, plain S4 store,
// fused 9-scalar BN stats (9 global atomics per block)
__global__ void accum_kernel(const unsigned* __restrict__ ebuf, const int* __restrict__ gcur,
                             const float4* __restrict__ xd, float4* __restrict__ S4,
                             float* __restrict__ stats) {
    __shared__ float S[4][BSZ][3];
    __shared__ float ls[4][9];
    int tid = threadIdx.x, b = blockIdx.x;
    int wv = tid >> 6;
    for (int j = tid; j < 4 * BSZ * 3; j += 256) ((float*)S)[j] = 0.f;
    __syncthreads();
    int cnt = gcur[b];
    int base = b * CAP;
    for (int e = tid; e < cnt; e += 256) {
        unsigned p = ebuf[base + e];
        float4 v = xd[p & SRC_MASK];
        int l = (int)(p >> 17);
        atomicAdd(&S[wv][l][0], v.x);
        atomicAdd(&S[wv][l][1], v.y);
        atomicAdd(&S[wv][l][2], v.z);
    }
    __syncthreads();
    float st[9];
#pragma unroll
    for (int q = 0; q < 9; ++q) st[q] = 0.f;
    if (tid < BSZ) {
        int n = (b << 7) + tid;
        if (n < N_NODES) {
            float4 self = xd[n];
            float sx = self.x + S[0][tid][0] + S[1][tid][0] + S[2][tid][0] + S[3][tid][0];
            float sy = self.y + S[0][tid][1] + S[1][tid][1] + S[2][tid][1] + S[3][tid][1];
            float sz = self.z + S[0][tid][2] + S[1][tid][2] + S[2][tid][2] + S[3][tid][2];
            S4[n] = make_float4(sx, sy, sz, self.w);
            float ax = self.w * sx, ay = self.w * sy, az = self.w * sz;
            st[0] = ax; st[1] = ay; st[2] = az;
            st[3] = ax * ax; st[4] = ax * ay; st[5] = ax * az;
            st[6] = ay * ay; st[7] = ay * az; st[8] = az * az;
        }
    }
    for (int m = 1; m < 64; m <<= 1)
#pragma unroll
        for (int q = 0; q < 9; ++q) st[q] += __shfl_xor(st[q], m);
    if ((tid & 63) == 0)
#pragma unroll
        for (int q = 0; q < 9; ++q) ls[wv][q] = st[q];
    __syncthreads();
    if (tid < 9) {
        float s = ls[0][tid] + ls[1][tid] + ls[2][tid] + ls[3][tid];
        atomicAdd(&stats[tid], s);
    }
}

// fused BN-fold + PReLU streaming output
__global__ void final_out_kernel(const float4* __restrict__ S4, const float* __restrict__ stats,
                                 const float* __restrict__ W, const float* __restrict__ bb,
                                 const float* __restrict__ gamma, const float* __restrict__ beta,
                                 const float* __restrict__ prelu, float* __restrict__ out) {
    __shared__ float cb[4 * HID];
    int tid = threadIdx.x;
    if (tid < HID) {
        int c = tid;
        float m1x = stats[0], m1y = stats[1], m1z = stats[2];
        float Mxx = stats[3], Mxy = stats[4], Mxz = stats[5];
        float Myy = stats[6], Myz = stats[7], Mzz = stats[8];
        float w0 = W[c], w1 = W[HID + c], w2 = W[2 * HID + c];
        const float invn = 1.0f / (float)N_NODES;
        float m1w = m1x * w0 + m1y * w1 + m1z * w2;
        float mean = m1w * invn + bb[c];
        float quad = w0 * w0 * Mxx + w1 * w1 * Myy + w2 * w2 * Mzz
                   + 2.f * (w0 * w1 * Mxy + w0 * w2 * Mxz + w1 * w2 * Myz);
        float ex2 = quad * invn + 2.f * bb[c] * m1w * invn + bb[c] * bb[c];
        float var = ex2 - mean * mean;
        float sc = gamma[c] * rsqrtf(var + BN_EPS);
        cb[c] = w0 * sc;
        cb[HID + c] = w1 * sc;
        cb[2 * HID + c] = w2 * sc;
        cb[3 * HID + c] = bb[c] * sc + (beta[c] - mean * sc);
    }
    __syncthreads();
    float a = prelu[0];
    int stride = gridDim.x * blockDim.x;
    for (int t = blockIdx.x * blockDim.x + tid; t < N_NODES * HID; t += stride) {
        int n = t >> 5, c = t & 31;
        float4 s = S4[n];
        float y = s.w * (s.x * cb[c] + s.y * cb[HID + c] + s.z * cb[2 * HID + c])
                + cb[3 * HID + c];
        out[t] = y >= 0.f ? y : a * y;
    }
}

// ============================ fallback (round-4) path ============================

__global__ void fb_count_kernel(const int* __restrict__ dst, int* __restrict__ cnt) {
    int e = blockIdx.x * blockDim.x + threadIdx.x;
    if (e < N_EDGES) atomicAdd(&cnt[dst[e]], 1);
}

__global__ void fb_xd_kernel(const float* __restrict__ x, const int* __restrict__ cnt,
                             float4* __restrict__ xd, float4* __restrict__ S4) {
    int n = blockIdx.x * blockDim.x + threadIdx.x;
    if (n >= N_NODES) return;
    float rd = rsqrtf(1.0f + (float)cnt[n]);
    float4 v = make_float4(x[3 * n] * rd, x[3 * n + 1] * rd, x[3 * n + 2] * rd, rd);
    xd[n] = v;
    S4[n] = v;
}

__global__ void fb_scatter_kernel(const int* __restrict__ src, const int* __restrict__ dst,
                                  const float4* __restrict__ xd, float4* __restrict__ S4) {
    int e = blockIdx.x * blockDim.x + threadIdx.x;
    if (e >= N_EDGES) return;
    int s = src[e], d = dst[e];
    float4 v = xd[s];
    float* p = (float*)&S4[d];
    atomicAdd(p + 0, v.x);
    atomicAdd(p + 1, v.y);
    atomicAdd(p + 2, v.z);
}

__global__ void fb_stats_kernel(const float4* __restrict__ S4, float* __restrict__ stats) {
    __shared__ float ls[4][9];
    int tid = threadIdx.x;
    int n = blockIdx.x * blockDim.x + tid;
    float st[9];
#pragma unroll
    for (int q = 0; q < 9; ++q) st[q] = 0.f;
    if (n < N_NODES) {
        float4 s = S4[n];
        float ax = s.w * s.x, ay = s.w * s.y, az = s.w * s.z;
        st[0] = ax; st[1] = ay; st[2] = az;
        st[3] = ax * ax; st[4] = ax * ay; st[5] = ax * az;
        st[6] = ay * ay; st[7] = ay * az; st[8] = az * az;
    }
    for (int m = 1; m < 64; m <<= 1)
#pragma unroll
        for (int q = 0; q < 9; ++q) st[q] += __shfl_xor(st[q], m);
    int wv = tid >> 6;
    if ((tid & 63) == 0)
#pragma unroll
        for (int q = 0; q < 9; ++q) ls[wv][q] = st[q];
    __syncthreads();
    if (tid < 9) {
        float s = ls[0][tid] + ls[1][tid] + ls[2][tid] + ls[3][tid];
        atomicAdd(&stats[tid], s);
    }
}

// ============================ launch ============================

extern "C" void kernel_launch(void* const* d_in, const int* in_sizes, int n_in,
                              void* d_out, int out_size, void* d_ws, size_t ws_size,
                              hipStream_t stream) {
    const float* x     = (const float*)d_in[0];
    const int*   ei    = (const int*)d_in[1];   // [2, E]: src row then dst row
    const float* W     = (const float*)d_in[2];
    const float* b     = (const float*)d_in[3];
    const float* gamma = (const float*)d_in[4];
    const float* beta  = (const float*)d_in[5];
    const float* prelu = (const float*)d_in[6];

    const int* src = ei;
    const int* dst = ei + N_EDGES;
    char* ws = (char*)d_ws;
    float* out = (float*)d_out;

    // ---- ws layout (main path), total 12,812,416 B ----
    // gcur  @ 0          int[782]          (3,128) -> pad 3,136
    // stats @ 3,136      float[16]         (64)    -> 3,200   <- memset covers [0,3200)
    // ebuf  @ 3,200      u32[NBUCK*CAP]    (9,609,216) -> 9,612,416
    // xd    @ 9,612,416  float4[100000]    (1,600,000) -> 11,212,416  (16B-aligned)
    // S4    @ 11,212,416 float4[100000]    (1,600,000) -> 12,812,416  (16B-aligned)
    const size_t NEEDED = 12812416;

    if (ws_size >= NEEDED) {
        int*      gcur  = (int*)(ws);
        float*    stats = (float*)(ws + 3136);
        unsigned* ebuf  = (unsigned*)(ws + 3200);
        float4*   xd    = (float4*)(ws + 9612416);
        float4*   S4    = (float4*)(ws + 11212416);

        hipMemsetAsync(ws, 0, 3200, stream);
        bin_kernel<<<NSL, 1024, 0, stream>>>(src, dst, gcur, ebuf);
        degxd_kernel<<<NBUCK, 256, 0, stream>>>(ebuf, gcur, x, xd);
        accum_kernel<<<NBUCK, 256, 0, stream>>>(ebuf, gcur, xd, S4, stats);
        final_out_kernel<<<2048, 256, 0, stream>>>(S4, stats, W, b, gamma, beta, prelu, out);
    } else {
        // fallback: round-4 direct-atomic path (ws need ~3.6 MB)
        int*    cnt   = (int*)(ws);
        float*  stats = (float*)(ws + 400000);
        float4* xd    = (float4*)(ws + 400640);
        float4* S4    = (float4*)(ws + 2000640);

        hipMemsetAsync(ws, 0, 400064, stream);
        fb_count_kernel<<<(N_EDGES + 255) / 256, 256, 0, stream>>>(dst, cnt);
        fb_xd_kernel<<<(N_NODES + 255) / 256, 256, 0, stream>>>(x, cnt, xd, S4);
        fb_scatter_kernel<<<(N_EDGES + 255) / 256, 256, 0, stream>>>(src, dst, xd, S4);
        fb_stats_kernel<<<(N_NODES + 255) / 256, 256, 0, stream>>>(S4, stats);
        final_out_kernel<<<2048, 256, 0, stream>>>(S4, stats, W, b, gamma, beta, prelu, out);
    }
}